// Round 4
// baseline (213.697 us; speedup 1.0000x reference)
//
#include <hip/hip_runtime.h>
#include <math.h>

#define SEQ   4096
#define NOBJ  32
#define IN_F  4
#define HID   64
#define IFEAT 8
#define NPAIR_HALF 496   // 32*31/2 unordered pairs

#define TWO_LOG2E 2.8853900817779268f   // 2*log2(e); g is pre-scaled by this

#if __has_builtin(__builtin_amdgcn_exp2f)
  #define EXP2F(x) __builtin_amdgcn_exp2f(x)
#else
  #define EXP2F(x) __expf((x) * 0.6931471805599453f)
#endif

// standard tanh for the (unscaled) u values: ~1e-7 abs error
__device__ __forceinline__ float tanh_fast(float x) {
  float e = __expf(x + x);
  float r = __builtin_amdgcn_rcpf(e + 1.0f);
  return fmaf(-2.0f, r, 1.0f);
}

// cumulative pair count before row i (i<j ordering): C(i) = i*(63-i)/2
__device__ __forceinline__ int pair_cum(int i) { return (i * (63 - i)) >> 1; }

// launch_bounds: (256,4) = VGPR cap 128. (256,8) forced VGPR<=64 -> 30MB of
// scratch spills (R1). LDS (~21KB) caps occupancy at 7 blocks/CU anyway.
__global__ __launch_bounds__(256, 4) void magnet_fused(
    const float* __restrict__ x,      // [S,32,4]
    const float* __restrict__ L1W,    // [64,4]
    const float* __restrict__ L1b,    // [64]
    const float* __restrict__ L2W,    // [64,64]
    const float* __restrict__ L2b,    // [64]
    const float* __restrict__ I1W,    // [64,64]
    const float* __restrict__ I2W,    // [8,64]
    const float* __restrict__ I3,     // [992,2,4]
    const float* __restrict__ S1W,    // [4,4]
    const float* __restrict__ S1b,    // [4]
    const float* __restrict__ S2W,    // [32,2,2]
    const float* __restrict__ S2b,    // [32,2]
    float* __restrict__ out)          // [S,32,2]
{
  // region A: sAt (phases 1-2), then sg (phases 3-4). sg = 32*68 = 2176 floats
  //           <= 64*36 = 2304. Row stride 68 floats = 272B (16B aligned, and
  //           bank stride 4: rows j, j+8 collide 4-way on b128 -> ~free).
  // region B: sBt (phase 2 write, phase 3 read)
  __shared__ __align__(16) float smem[2 * HID * 36];
  float (*sAt)[36] = (float(*)[36])smem;
  float (*sBt)[36] = (float(*)[36])(smem + HID * 36);
  float (*sg)[68]  = (float(*)[68])smem;   // aliases sAt
  // I2W staged once, transposed for uniform float4 broadcast reads:
  // sI2W[hb][f][c] = I2W[f][hb*4+c]
  __shared__ __align__(16) float sI2W[16][IFEAT][4];
  __shared__ float sx[NOBJ][IN_F];
  __shared__ float sacc[NOBJ][2];

  const int t = threadIdx.x;
  const int s = blockIdx.x;

  if (t < NOBJ * IN_F) ((float*)sx)[t] = x[s * (NOBJ * IN_F) + t];
  if (t < NOBJ * 2)    ((float*)sacc)[t] = 0.0f;
  #pragma unroll
  for (int idx = t; idx < IFEAT * HID; idx += 256) {   // 2 iters
    const int f = idx >> 6, h = idx & 63;
    sI2W[h >> 2][f][h & 3] = I2W[idx];
  }
  __syncthreads();

  // ---- phase 1: h1 = relu(x @ L1W^T + L1b) -> sAt[k][n] ----
  {
    const int n = t & 31, kb = (t >> 5) * 8;
    const float x0 = sx[n][0], x1 = sx[n][1], x2 = sx[n][2], x3 = sx[n][3];
    #pragma unroll
    for (int r = 0; r < 8; ++r) {
      const int k = kb + r;
      const float4 w = *(const float4*)(L1W + k * 4);
      float a = L1b[k];
      a = fmaf(x0, w.x, a); a = fmaf(x1, w.y, a);
      a = fmaf(x2, w.z, a); a = fmaf(x3, w.w, a);
      sAt[k][n] = fmaxf(a, 0.0f);
    }
  }
  __syncthreads();

  const int ho = t & 63;
  const int nb = (t >> 6) * 8;

  // ---- phase 2: h2 = relu(h1 @ L2W^T + L2b) -> sBt[ho][n] ----
  {
    float acc[8];
    const float b = L2b[ho];
    #pragma unroll
    for (int r = 0; r < 8; ++r) acc[r] = b;
    const float* wr = L2W + ho * HID;
    #pragma unroll
    for (int k4 = 0; k4 < HID; k4 += 4) {
      const float4 w = *(const float4*)(wr + k4);
      #pragma unroll
      for (int kk = 0; kk < 4; ++kk) {
        const float wk = (&w.x)[kk];
        const float4 a0 = *(const float4*)&sAt[k4 + kk][nb];
        const float4 a1 = *(const float4*)&sAt[k4 + kk][nb + 4];
        acc[0] = fmaf(wk, a0.x, acc[0]); acc[1] = fmaf(wk, a0.y, acc[1]);
        acc[2] = fmaf(wk, a0.z, acc[2]); acc[3] = fmaf(wk, a0.w, acc[3]);
        acc[4] = fmaf(wk, a1.x, acc[4]); acc[5] = fmaf(wk, a1.y, acc[5]);
        acc[6] = fmaf(wk, a1.z, acc[6]); acc[7] = fmaf(wk, a1.w, acc[7]);
      }
    }
    #pragma unroll
    for (int r = 0; r < 8; ++r) sBt[ho][nb + r] = fmaxf(acc[r], 0.0f);
  }
  __syncthreads();

  // ---- phase 3: g = (h2 @ I1W^T) * 2log2e -> sg[n][ho] ----
  // sg aliases sAt; sAt fully consumed in phase 2, barrier above protects.
  {
    float acc[8] = {0.f,0.f,0.f,0.f,0.f,0.f,0.f,0.f};
    const float* wr = I1W + ho * HID;
    #pragma unroll
    for (int k4 = 0; k4 < HID; k4 += 4) {
      const float4 w = *(const float4*)(wr + k4);
      #pragma unroll
      for (int kk = 0; kk < 4; ++kk) {
        const float wk = (&w.x)[kk];
        const float4 a0 = *(const float4*)&sBt[k4 + kk][nb];
        const float4 a1 = *(const float4*)&sBt[k4 + kk][nb + 4];
        acc[0] = fmaf(wk, a0.x, acc[0]); acc[1] = fmaf(wk, a0.y, acc[1]);
        acc[2] = fmaf(wk, a0.z, acc[2]); acc[3] = fmaf(wk, a0.w, acc[3]);
        acc[4] = fmaf(wk, a1.x, acc[4]); acc[5] = fmaf(wk, a1.y, acc[5]);
        acc[6] = fmaf(wk, a1.z, acc[6]); acc[7] = fmaf(wk, a1.w, acc[7]);
      }
    }
    #pragma unroll
    for (int r = 0; r < 8; ++r) sg[nb + r][ho] = acc[r] * TWO_LOG2E;
  }
  __syncthreads();

  // ---- phase 4: unordered pairs (i<j); antisymmetry gives (j,i) for free ----
  // g pre-scaled by 2log2e: tanh(gi-gj) = 1 - 2*rcp(exp2(g'i-g'j)+1).
  for (int q = t; q < NPAIR_HALF; q += 256) {
    int i = (int)((63.0f - sqrtf(3969.0f - 8.0f * (float)q)) * 0.5f);
    if (i > 0 && pair_cum(i) > q) --i;            // fp rounding fixup
    if (pair_cum(i + 1) <= q)     ++i;
    const int j = i + 1 + (q - pair_cum(i));

    const float4* gi = (const float4*)&sg[i][0];
    const float4* gj = (const float4*)&sg[j][0];

    float u[IFEAT] = {0.f,0.f,0.f,0.f,0.f,0.f,0.f,0.f};
    #pragma unroll 4
    for (int hb = 0; hb < 16; ++hb) {
      const float4 a = gi[hb];
      const float4 b = gj[hb];
      float th[4];
      #pragma unroll
      for (int c = 0; c < 4; ++c) {
        const float d = (&a.x)[c] - (&b.x)[c];
        const float e = EXP2F(d);
        const float r = __builtin_amdgcn_rcpf(e + 1.0f);
        th[c] = fmaf(-2.0f, r, 1.0f);
      }
      #pragma unroll
      for (int f = 0; f < IFEAT; ++f) {
        const float4 w = *(const float4*)&sI2W[hb][f][0];  // uniform -> bcast
        float acc = u[f];
        acc = fmaf(w.x, th[0], acc);
        acc = fmaf(w.y, th[1], acc);
        acc = fmaf(w.z, th[2], acc);
        acc = fmaf(w.w, th[3], acc);
        u[f] = acc;
      }
    }

    // row-major pair table index: p(a,b) = a*31 + b - (b>a)
    const float* cij = I3 + (i * 31 + (j - 1)) * 8;   // j > i
    const float* cji = I3 + (j * 31 + i) * 8;         // i < j
    #pragma unroll
    for (int d = 0; d < 2; ++d) {
      float vi = 0.f, vj = 0.f;
      #pragma unroll
      for (int k = 0; k < 4; ++k) {
        const float v = tanh_fast(u[d * 4 + k]);
        vi = fmaf(cij[d * 4 + k],  v, vi);
        vj = fmaf(cji[d * 4 + k], -v, vj);
      }
      atomicAdd(&sacc[i][d], vi);
      atomicAdd(&sacc[j][d], vj);
    }
  }
  __syncthreads();

  // ---- epilogue: self term + store ----
  if (t < NOBJ * 2) {
    const int i = t >> 1, d = t & 1;
    float res = S2b[t] + sacc[i][d];
    #pragma unroll
    for (int k = 0; k < 2; ++k) {
      const int f = d * 2 + k;
      float hs = S1b[f];
      hs = fmaf(sx[i][0], S1W[f * 4 + 0], hs);
      hs = fmaf(sx[i][1], S1W[f * 4 + 1], hs);
      hs = fmaf(sx[i][2], S1W[f * 4 + 2], hs);
      hs = fmaf(sx[i][3], S1W[f * 4 + 3], hs);
      hs = fmaxf(hs, 0.0f);
      res = fmaf(hs, S2W[i * 4 + d * 2 + k], res);
    }
    out[s * (NOBJ * 2) + t] = res;
  }
}

extern "C" void kernel_launch(void* const* d_in, const int* in_sizes, int n_in,
                              void* d_out, int out_size, void* d_ws, size_t ws_size,
                              hipStream_t stream) {
  const float* x   = (const float*)d_in[0];
  const float* L1W = (const float*)d_in[1];
  const float* L1b = (const float*)d_in[2];
  const float* L2W = (const float*)d_in[3];
  const float* L2b = (const float*)d_in[4];
  const float* I1W = (const float*)d_in[5];
  const float* I2W = (const float*)d_in[6];
  const float* I3  = (const float*)d_in[7];
  const float* S1W = (const float*)d_in[8];
  const float* S1b = (const float*)d_in[9];
  const float* S2W = (const float*)d_in[10];
  const float* S2b = (const float*)d_in[11];
  float* outp = (float*)d_out;

  magnet_fused<<<SEQ, 256, 0, stream>>>(x, L1W, L1b, L2W, L2b, I1W, I2W, I3,
                                        S1W, S1b, S2W, S2b, outp);
}

// Round 5
// 161.309 us; speedup vs baseline: 1.3248x; 1.3248x over previous
//
#include <hip/hip_runtime.h>
#include <math.h>

#define SEQ   4096
#define NOBJ  32
#define IN_F  4
#define HID   64
#define IFEAT 8
#define NPAIR_HALF 496   // 32*31/2 unordered pairs

#define TWO_LOG2E 2.8853900817779268f   // 2*log2(e)

#if __has_builtin(__builtin_amdgcn_exp2f)
  #define EXP2F(x) __builtin_amdgcn_exp2f(x)
#else
  #define EXP2F(x) exp2f(x)
#endif

// tanh via exp2: tanh(x) = 1 - 2/(exp2(x*2log2e)+1)
__device__ __forceinline__ float tanh_u(float x) {
  float e = EXP2F(x * TWO_LOG2E);
  float r = __builtin_amdgcn_rcpf(e + 1.0f);
  return fmaf(-2.0f, r, 1.0f);
}

// cumulative pair count before row i (i<j ordering): C(i) = i*(63-i)/2
__device__ __forceinline__ int pair_cum(int i) { return (i * (63 - i)) >> 1; }

__device__ __forceinline__ void pair_decode(int q, int& i, int& j) {
  int ii = (int)((63.0f - sqrtf(3969.0f - 8.0f * (float)q)) * 0.5f);
  if (ii > 0 && pair_cum(ii) > q) --ii;   // fp rounding fixups
  if (pair_cum(ii + 1) <= q)     ++ii;
  i = ii;
  j = ii + 1 + (q - pair_cum(ii));
}

// (256,4): VGPR cap 128. (256,8) caused 30MB scratch spill (R1).
__global__ __launch_bounds__(256, 4) void magnet_fused(
    const float* __restrict__ x,      // [S,32,4]
    const float* __restrict__ L1W,    // [64,4]
    const float* __restrict__ L1b,    // [64]
    const float* __restrict__ L2W,    // [64,64]
    const float* __restrict__ L2b,    // [64]
    const float* __restrict__ I1W,    // [64,64]
    const float* __restrict__ I2W,    // [8,64]
    const float* __restrict__ I3,     // [992,2,4]
    const float* __restrict__ S1W,    // [4,4]
    const float* __restrict__ S1b,    // [4]
    const float* __restrict__ S2W,    // [32,2,2]
    const float* __restrict__ S2b,    // [32,2]
    float* __restrict__ out)          // [S,32,2]
{
  // region A: sAt (ph 1-2) then sE (ph 3-4); region B: sBt (ph 2-3) then sEm.
  // E rows stride 68 floats (16B aligned); 32*68=2176 <= 64*36=2304.
  __shared__ __align__(16) float smem[2 * HID * 36];
  float (*sAt)[36] = (float(*)[36])smem;
  float (*sBt)[36] = (float(*)[36])(smem + HID * 36);
  float (*sE)[68]  = (float(*)[68])smem;               // exp2(+g')
  float (*sEm)[68] = (float(*)[68])(smem + HID * 36);  // exp2(-g')
  __shared__ __align__(16) float pairval[NPAIR_HALF][4]; // {vi0,vi1,vj0,vj1}
  __shared__ float sx[NOBJ][IN_F];
  __shared__ float sW[IFEAT];        // row sums of I2W

  const int t = threadIdx.x;
  const int s = blockIdx.x;

  if (t < NOBJ * IN_F) ((float*)sx)[t] = x[s * (NOBJ * IN_F) + t];
  if (t < IFEAT) {                   // W[f] = sum_h I2W[f][h]
    float a = 0.0f;
    const float4* w = (const float4*)(I2W + t * HID);
    #pragma unroll
    for (int c = 0; c < 16; ++c) { float4 v = w[c]; a += (v.x + v.y) + (v.z + v.w); }
    sW[t] = a;
  }
  __syncthreads();

  // ---- phase 1: h1 = relu(x @ L1W^T + L1b) -> sAt[k][n] ----
  {
    const int n = t & 31, kb = (t >> 5) * 8;
    const float x0 = sx[n][0], x1 = sx[n][1], x2 = sx[n][2], x3 = sx[n][3];
    #pragma unroll
    for (int r = 0; r < 8; ++r) {
      const int k = kb + r;
      const float4 w = *(const float4*)(L1W + k * 4);
      float a = L1b[k];
      a = fmaf(x0, w.x, a); a = fmaf(x1, w.y, a);
      a = fmaf(x2, w.z, a); a = fmaf(x3, w.w, a);
      sAt[k][n] = fmaxf(a, 0.0f);
    }
  }
  __syncthreads();

  const int ho = t & 63;
  const int nb = (t >> 6) * 8;

  // ---- phase 2: h2 = relu(h1 @ L2W^T + L2b) -> sBt[ho][n] ----
  {
    float acc[8];
    const float b = L2b[ho];
    #pragma unroll
    for (int r = 0; r < 8; ++r) acc[r] = b;
    const float* wr = L2W + ho * HID;
    #pragma unroll
    for (int k4 = 0; k4 < HID; k4 += 4) {
      const float4 w = *(const float4*)(wr + k4);
      #pragma unroll
      for (int kk = 0; kk < 4; ++kk) {
        const float wk = (&w.x)[kk];
        const float4 a0 = *(const float4*)&sAt[k4 + kk][nb];
        const float4 a1 = *(const float4*)&sAt[k4 + kk][nb + 4];
        acc[0] = fmaf(wk, a0.x, acc[0]); acc[1] = fmaf(wk, a0.y, acc[1]);
        acc[2] = fmaf(wk, a0.z, acc[2]); acc[3] = fmaf(wk, a0.w, acc[3]);
        acc[4] = fmaf(wk, a1.x, acc[4]); acc[5] = fmaf(wk, a1.y, acc[5]);
        acc[6] = fmaf(wk, a1.z, acc[6]); acc[7] = fmaf(wk, a1.w, acc[7]);
      }
    }
    #pragma unroll
    for (int r = 0; r < 8; ++r) sBt[ho][nb + r] = fmaxf(acc[r], 0.0f);
  }
  __syncthreads();

  // ---- phase 3: g = h2 @ I1W^T; store E=exp2(g'), Em=exp2(-g'), g'=2log2e*g
  {
    float acc[8] = {0.f,0.f,0.f,0.f,0.f,0.f,0.f,0.f};
    const float* wr = I1W + ho * HID;
    #pragma unroll
    for (int k4 = 0; k4 < HID; k4 += 4) {
      const float4 w = *(const float4*)(wr + k4);
      #pragma unroll
      for (int kk = 0; kk < 4; ++kk) {
        const float wk = (&w.x)[kk];
        const float4 a0 = *(const float4*)&sBt[k4 + kk][nb];
        const float4 a1 = *(const float4*)&sBt[k4 + kk][nb + 4];
        acc[0] = fmaf(wk, a0.x, acc[0]); acc[1] = fmaf(wk, a0.y, acc[1]);
        acc[2] = fmaf(wk, a0.z, acc[2]); acc[3] = fmaf(wk, a0.w, acc[3]);
        acc[4] = fmaf(wk, a1.x, acc[4]); acc[5] = fmaf(wk, a1.y, acc[5]);
        acc[6] = fmaf(wk, a1.z, acc[6]); acc[7] = fmaf(wk, a1.w, acc[7]);
      }
    }
    __syncthreads();   // every thread done reading sBt before Em overwrites it
    #pragma unroll
    for (int r = 0; r < 8; ++r) {
      float gp = acc[r] * TWO_LOG2E;
      gp = fminf(fmaxf(gp, -60.0f), 60.0f);  // E*Em stays within 2^+-120
      sE [nb + r][ho] = EXP2F(gp);
      sEm[nb + r][ho] = EXP2F(-gp);
    }
  }
  __syncthreads();

  // ---- phase 4a: 2 fused pairs/thread; tanh(gi-gj) -> 1 - 2*rcp(Ei*Emj+1)
  // u[f] = sum_h w*th = W[f] - 2*sum_h w*r. No atomics: results -> pairval.
  {
    int i1, j1, i2, j2;
    pair_decode(t, i1, j1);
    const bool has2 = (t + 256) < NPAIR_HALF;
    pair_decode(has2 ? t + 256 : 0, i2, j2);

    float sWr[IFEAT];
    #pragma unroll
    for (int f = 0; f < IFEAT; ++f) sWr[f] = sW[f];

    float da[IFEAT] = {0.f,0.f,0.f,0.f,0.f,0.f,0.f,0.f};
    float db[IFEAT] = {0.f,0.f,0.f,0.f,0.f,0.f,0.f,0.f};
    const float4* Ei1 = (const float4*)&sE [i1][0];
    const float4* Mj1 = (const float4*)&sEm[j1][0];
    const float4* Ei2 = (const float4*)&sE [i2][0];
    const float4* Mj2 = (const float4*)&sEm[j2][0];

    #pragma unroll 4
    for (int hb = 0; hb < 16; ++hb) {
      const float4 a1 = Ei1[hb], b1 = Mj1[hb];
      const float4 a2 = Ei2[hb], b2 = Mj2[hb];
      float r1[4], r2[4];
      #pragma unroll
      for (int c = 0; c < 4; ++c) {
        r1[c] = __builtin_amdgcn_rcpf(fmaf((&a1.x)[c], (&b1.x)[c], 1.0f));
        r2[c] = __builtin_amdgcn_rcpf(fmaf((&a2.x)[c], (&b2.x)[c], 1.0f));
      }
      #pragma unroll
      for (int f = 0; f < IFEAT; ++f) {
        const float4 w = *(const float4*)(I2W + f * HID + hb * 4); // uniform->s_load
        da[f] = fmaf(w.x, r1[0], da[f]); da[f] = fmaf(w.y, r1[1], da[f]);
        da[f] = fmaf(w.z, r1[2], da[f]); da[f] = fmaf(w.w, r1[3], da[f]);
        db[f] = fmaf(w.x, r2[0], db[f]); db[f] = fmaf(w.y, r2[1], db[f]);
        db[f] = fmaf(w.z, r2[2], db[f]); db[f] = fmaf(w.w, r2[3], db[f]);
      }
    }

    {
      const float* cij = I3 + (i1 * 31 + (j1 - 1)) * 8;
      const float* cji = I3 + (j1 * 31 + i1) * 8;
      float vi0 = 0.f, vi1 = 0.f, vj0 = 0.f, vj1 = 0.f;
      #pragma unroll
      for (int k = 0; k < 4; ++k) {
        const float v = tanh_u(fmaf(-2.0f, da[k], sWr[k]));
        vi0 = fmaf(cij[k],  v, vi0);
        vj0 = fmaf(cji[k], -v, vj0);
      }
      #pragma unroll
      for (int k = 0; k < 4; ++k) {
        const float v = tanh_u(fmaf(-2.0f, da[4 + k], sWr[4 + k]));
        vi1 = fmaf(cij[4 + k],  v, vi1);
        vj1 = fmaf(cji[4 + k], -v, vj1);
      }
      float4 pv; pv.x = vi0; pv.y = vi1; pv.z = vj0; pv.w = vj1;
      *(float4*)&pairval[t][0] = pv;
    }
    if (has2) {
      const float* cij = I3 + (i2 * 31 + (j2 - 1)) * 8;
      const float* cji = I3 + (j2 * 31 + i2) * 8;
      float vi0 = 0.f, vi1 = 0.f, vj0 = 0.f, vj1 = 0.f;
      #pragma unroll
      for (int k = 0; k < 4; ++k) {
        const float v = tanh_u(fmaf(-2.0f, db[k], sWr[k]));
        vi0 = fmaf(cij[k],  v, vi0);
        vj0 = fmaf(cji[k], -v, vj0);
      }
      #pragma unroll
      for (int k = 0; k < 4; ++k) {
        const float v = tanh_u(fmaf(-2.0f, db[4 + k], sWr[4 + k]));
        vi1 = fmaf(cij[4 + k],  v, vi1);
        vj1 = fmaf(cji[4 + k], -v, vj1);
      }
      float4 pv; pv.x = vi0; pv.y = vi1; pv.z = vj0; pv.w = vj1;
      *(float4*)&pairval[t + 256][0] = pv;
    }
  }
  __syncthreads();

  // ---- phase 4b + epilogue: row-gather reduction (no atomics) ----
  if (t < 64) {
    const int i = t >> 1, d = t & 1;
    float sum = 0.0f;
    for (int j = 0; j < i; ++j)                    // pair (j,i), take vj slot
      sum += pairval[pair_cum(j) + (i - j - 1)][2 + d];
    const int base = pair_cum(i);
    for (int m = 0; m < 31 - i; ++m)               // pair (i,*), consecutive q
      sum += pairval[base + m][d];

    float res = S2b[t] + sum;
    #pragma unroll
    for (int k = 0; k < 2; ++k) {
      const int f = d * 2 + k;
      float hs = S1b[f];
      hs = fmaf(sx[i][0], S1W[f * 4 + 0], hs);
      hs = fmaf(sx[i][1], S1W[f * 4 + 1], hs);
      hs = fmaf(sx[i][2], S1W[f * 4 + 2], hs);
      hs = fmaf(sx[i][3], S1W[f * 4 + 3], hs);
      hs = fmaxf(hs, 0.0f);
      res = fmaf(hs, S2W[i * 4 + d * 2 + k], res);
    }
    out[s * (NOBJ * 2) + t] = res;
  }
}

extern "C" void kernel_launch(void* const* d_in, const int* in_sizes, int n_in,
                              void* d_out, int out_size, void* d_ws, size_t ws_size,
                              hipStream_t stream) {
  const float* x   = (const float*)d_in[0];
  const float* L1W = (const float*)d_in[1];
  const float* L1b = (const float*)d_in[2];
  const float* L2W = (const float*)d_in[3];
  const float* L2b = (const float*)d_in[4];
  const float* I1W = (const float*)d_in[5];
  const float* I2W = (const float*)d_in[6];
  const float* I3  = (const float*)d_in[7];
  const float* S1W = (const float*)d_in[8];
  const float* S1b = (const float*)d_in[9];
  const float* S2W = (const float*)d_in[10];
  const float* S2b = (const float*)d_in[11];
  float* outp = (float*)d_out;

  magnet_fused<<<SEQ, 256, 0, stream>>>(x, L1W, L1b, L2W, L2b, I1W, I2W, I3,
                                        S1W, S1b, S2W, S2b, outp);
}